// Round 6
// baseline (1321.175 us; speedup 1.0000x reference)
//
#include <hip/hip_runtime.h>

#define N_USERS 50000
#define NTOT    100000
#define D       64
#define NNZ     3200000
#define B       1024
#define SCAN_BLOCKS ((NTOT + 1023) / 1024)   // 98
#define NBUCK ((NTOT + 255) / 256)           // 391
#define EPB 4096
#define BINA_BLOCKS ((NNZ + EPB - 1) / EPB)  // 782
#define SPMM_GRID 1024
#define NGROUPS (NTOT / 8)                   // 12500

__device__ __forceinline__ unsigned short f2bf(float f) {
  unsigned u = __float_as_uint(f);
  unsigned r = (u + 0x7FFFu + ((u >> 16) & 1u)) >> 16;
  return (unsigned short)r;
}
__device__ __forceinline__ float bf2f(unsigned short s) {
  return __uint_as_float(((unsigned)s) << 16);
}

// ---------- CSR build ----------
__global__ __launch_bounds__(256) void hist_kernel(const int* __restrict__ row,
                                                   int* __restrict__ counts) {
  unsigned e = blockIdx.x * 256u + threadIdx.x;
  if (e < NNZ) atomicAdd(&counts[row[e]], 1);
}

__global__ __launch_bounds__(1024) void scanA_kernel(const int* __restrict__ counts,
                                                     int* __restrict__ row_ptr,
                                                     int* __restrict__ blk_sums) {
  __shared__ int s[1024];
  int t = threadIdx.x;
  int gid = blockIdx.x * 1024 + t;
  int x = (gid < NTOT) ? counts[gid] : 0;
  s[t] = x;
  __syncthreads();
  #pragma unroll
  for (int off = 1; off < 1024; off <<= 1) {
    int v = (t >= off) ? s[t - off] : 0;
    __syncthreads();
    s[t] += v;
    __syncthreads();
  }
  if (gid < NTOT) row_ptr[gid] = s[t] - x;
  if (t == 1023) blk_sums[blockIdx.x] = s[t];
}

__global__ __launch_bounds__(128) void scanB_kernel(int* __restrict__ blk_sums,
                                                    int* __restrict__ blk_off) {
  __shared__ int s[128];
  int t = threadIdx.x;
  int x = (t < SCAN_BLOCKS) ? blk_sums[t] : 0;
  s[t] = x;
  __syncthreads();
  #pragma unroll
  for (int off = 1; off < 128; off <<= 1) {
    int v = (t >= off) ? s[t - off] : 0;
    __syncthreads();
    s[t] += v;
    __syncthreads();
  }
  if (t < SCAN_BLOCKS) blk_off[t] = s[t] - x;
}

__global__ __launch_bounds__(1024) void scanC2_kernel(int* __restrict__ row_ptr,
                                                      const int* __restrict__ blk_off) {
  int gid = blockIdx.x * 1024 + threadIdx.x;
  if (gid < NTOT) row_ptr[gid] += blk_off[blockIdx.x];
  if (gid == 0) row_ptr[NTOT] = NNZ;
}

__global__ __launch_bounds__(1024) void scanC_kernel(int* __restrict__ row_ptr,
                                                     int* __restrict__ cursor,
                                                     const int* __restrict__ blk_off) {
  int gid = blockIdx.x * 1024 + threadIdx.x;
  if (gid < NTOT) {
    int v = row_ptr[gid] + blk_off[blockIdx.x];
    row_ptr[gid] = v;
    cursor[gid] = v;
  }
  if (gid == 0) row_ptr[NTOT] = NNZ;
}

__global__ __launch_bounds__(256) void bcur_init_kernel(const int* __restrict__ row_ptr,
                                                        int* __restrict__ bcur) {
  int t = blockIdx.x * 256 + threadIdx.x;
  if (t < NBUCK) bcur[t] = row_ptr[t << 8];
}

__global__ __launch_bounds__(256) void binA_kernel(
    const int* __restrict__ row, const int* __restrict__ col,
    const float* __restrict__ val, int* __restrict__ bcur,
    int2* __restrict__ temp) {
  __shared__ int hist[NBUCK];
  __shared__ int base[NBUCK];
  int t = threadIdx.x;
  for (int i = t; i < NBUCK; i += 256) hist[i] = 0;
  __syncthreads();
  int e0 = blockIdx.x * EPB + t;
  int xp[16], yb[16], bk[16], ofs[16];
  #pragma unroll
  for (int i = 0; i < 16; ++i) {
    int e = e0 + i * 256;
    bk[i] = -1;
    if (e < NNZ) {
      int r = row[e];
      int b = r >> 8;
      xp[i] = col[e] | ((r & 255) << 17);
      yb[i] = __float_as_int(val[e]);
      bk[i] = b;
      ofs[i] = atomicAdd(&hist[b], 1);
    }
  }
  __syncthreads();
  for (int i = t; i < NBUCK; i += 256) {
    int h = hist[i];
    base[i] = h ? atomicAdd(&bcur[i], h) : 0;
  }
  __syncthreads();
  #pragma unroll
  for (int i = 0; i < 16; ++i) {
    if (bk[i] >= 0) {
      int2 p; p.x = xp[i]; p.y = yb[i];
      temp[base[bk[i]] + ofs[i]] = p;
    }
  }
}

__global__ __launch_bounds__(1024) void binB_kernel(
    const int* __restrict__ row_ptr, const int2* __restrict__ temp,
    int2* __restrict__ epair) {
  __shared__ int cur[256];
  int b = blockIdx.x, t = threadIdx.x;
  int r0 = b << 8;
  int nr = min(256, NTOT - r0);
  if (t < nr) cur[t] = row_ptr[r0 + t];
  __syncthreads();
  int lo = row_ptr[r0], hi = row_ptr[r0 + nr];
  for (int i = lo + t; i < hi; i += 1024) {
    int2 p = temp[i];
    int rlow = (p.x >> 17) & 255;
    int pos = atomicAdd(&cur[rlow], 1);
    int2 q; q.x = p.x & 0x1FFFF; q.y = p.y;
    epair[pos] = q;
  }
}

// Per-row bitonic sort by column (64-chunks). Pure reorder: sum unchanged.
__global__ __launch_bounds__(512) void sort_rows_kernel(const int* __restrict__ row_ptr,
                                                        int2* __restrict__ epair) {
  int lane = threadIdx.x & 63;
  int w = threadIdx.x >> 6;
  int r = blockIdx.x * 8 + w;
  int rp0 = row_ptr[r], rp1 = row_ptr[r + 1];
  for (int base = rp0; base < rp1; base += 64) {
    int idx = base + lane;
    bool ok = idx < rp1;
    int c = 0x7FFFFFFF, v = 0x7FFFFFFF;
    if (ok) { int2 p = epair[idx]; c = p.x; v = p.y; }
    #pragma unroll
    for (int k = 2; k <= 64; k <<= 1) {
      #pragma unroll
      for (int jj = k >> 1; jj > 0; jj >>= 1) {
        int pc = __shfl_xor(c, jj);
        int pv = __shfl_xor(v, jj);
        bool up = ((lane & k) == 0);
        bool lower = ((lane & jj) == 0);
        bool gt = (c > pc) || (c == pc && (unsigned)v > (unsigned)pv);
        bool takeMin = (lower == up);
        bool swap = takeMin ? gt : !gt;
        c = swap ? pc : c;
        v = swap ? pv : v;
      }
    }
    if (ok) { int2 o; o.x = c; o.y = v; epair[idx] = o; }
  }
}

// ---------- degree-sorted row permutation (descending) ----------
__global__ __launch_bounds__(256) void deg_hist_kernel(const int* __restrict__ row_ptr,
                                                       int* __restrict__ dhist) {
  int r = blockIdx.x * 256 + threadIdx.x;
  if (r < NTOT) {
    int deg = row_ptr[r + 1] - row_ptr[r];
    atomicAdd(&dhist[min(deg, 255)], 1);
  }
}

__global__ __launch_bounds__(256) void deg_scan_kernel(const int* __restrict__ dhist,
                                                       int* __restrict__ dcur) {
  __shared__ int s[256];
  int t = threadIdx.x;
  s[t] = dhist[t];
  __syncthreads();
  int acc = 0;
  for (int c = t + 1; c < 256; ++c) acc += s[c];  // suffix sum -> descending order
  dcur[t] = acc;
}

__global__ __launch_bounds__(256) void deg_scatter_kernel(const int* __restrict__ row_ptr,
                                                          int* __restrict__ dcur,
                                                          int* __restrict__ perm) {
  int r = blockIdx.x * 256 + threadIdx.x;
  if (r < NTOT) {
    int deg = row_ptr[r + 1] - row_ptr[r];
    int pos = atomicAdd(&dcur[min(deg, 255)], 1);
    perm[pos] = r;
  }
}

// f32 ego -> bf16 shadow
__global__ __launch_bounds__(256) void tobf_kernel(const float4* __restrict__ src,
                                                   ushort4* __restrict__ dst) {
  int i = blockIdx.x * 256 + threadIdx.x;
  if (i < NTOT * D / 4) {
    float4 f = src[i];
    ushort4 o;
    o.x = f2bf(f.x); o.y = f2bf(f.y); o.z = f2bf(f.z); o.w = f2bf(f.w);
    dst[i] = o;
  }
}

// ---------- fused CSR SpMM (bf16, 16 lanes/edge, perm-ordered, persistent) ----------
__global__ __launch_bounds__(512) void spmm_xform_bf_kernel(
    const int* __restrict__ perm, const int* __restrict__ row_ptr,
    const int2* __restrict__ epair,
    const float* __restrict__ ego_in, const unsigned short* __restrict__ bf_in,
    float* __restrict__ ego_out, unsigned short* __restrict__ bf_out,
    const float* __restrict__ Wg, const float* __restrict__ bg,
    const float* __restrict__ Wb, const float* __restrict__ bb) {
  __shared__ float sWg[64][65];
  __shared__ float sWb[64][65];
  __shared__ float sS[8][64];
  __shared__ float sH[8][64];
  int t = threadIdx.x;
  for (int i = t; i < 4096; i += 512) {
    sWg[i >> 6][i & 63] = Wg[i];
    sWb[i >> 6][i & 63] = Wb[i];
  }
  __syncthreads();

  int lane = t & 63;
  int w = t >> 6;                 // wave 0..7
  int es = lane >> 4;             // edge slot 0..3
  int q  = lane & 15;             // dim quad
  const ushort4* bfv = (const ushort4*)bf_in;
  float bias = bg[lane] + bb[lane];

  for (int grp = blockIdx.x; grp < NGROUPS; grp += gridDim.x) {
    int r = perm[grp * 8 + w];
    int rp0 = row_ptr[r], rp1 = row_ptr[r + 1];
    float4 A0 = {0.f, 0.f, 0.f, 0.f}, A1 = A0, A2 = A0, A3 = A0;
    if (rp0 < rp1) {
      int last = rp1 - 1;
      int2 c0 = epair[min(rp0 + es, last)];
      int2 c1 = epair[min(rp0 + 4 + es, last)];
      int2 c2 = epair[min(rp0 + 8 + es, last)];
      int2 c3 = epair[min(rp0 + 12 + es, last)];
      for (int j = rp0; j < rp1; j += 16) {
        int jn = j + 16;
        int2 n0 = epair[min(jn + es, last)];
        int2 n1 = epair[min(jn + 4 + es, last)];
        int2 n2 = epair[min(jn + 8 + es, last)];
        int2 n3 = epair[min(jn + 12 + es, last)];
        ushort4 u0 = bfv[c0.x * 16 + q];
        ushort4 u1 = bfv[c1.x * 16 + q];
        ushort4 u2 = bfv[c2.x * 16 + q];
        ushort4 u3 = bfv[c3.x * 16 + q];
        float v0 = (j + es      < rp1) ? __int_as_float(c0.y) : 0.f;
        float v1 = (j + 4 + es  < rp1) ? __int_as_float(c1.y) : 0.f;
        float v2 = (j + 8 + es  < rp1) ? __int_as_float(c2.y) : 0.f;
        float v3 = (j + 12 + es < rp1) ? __int_as_float(c3.y) : 0.f;
        A0.x = fmaf(v0, bf2f(u0.x), A0.x); A0.y = fmaf(v0, bf2f(u0.y), A0.y);
        A0.z = fmaf(v0, bf2f(u0.z), A0.z); A0.w = fmaf(v0, bf2f(u0.w), A0.w);
        A1.x = fmaf(v1, bf2f(u1.x), A1.x); A1.y = fmaf(v1, bf2f(u1.y), A1.y);
        A1.z = fmaf(v1, bf2f(u1.z), A1.z); A1.w = fmaf(v1, bf2f(u1.w), A1.w);
        A2.x = fmaf(v2, bf2f(u2.x), A2.x); A2.y = fmaf(v2, bf2f(u2.y), A2.y);
        A2.z = fmaf(v2, bf2f(u2.z), A2.z); A2.w = fmaf(v2, bf2f(u2.w), A2.w);
        A3.x = fmaf(v3, bf2f(u3.x), A3.x); A3.y = fmaf(v3, bf2f(u3.y), A3.y);
        A3.z = fmaf(v3, bf2f(u3.z), A3.z); A3.w = fmaf(v3, bf2f(u3.w), A3.w);
        c0 = n0; c1 = n1; c2 = n2; c3 = n3;
      }
    }
    float4 S;
    S.x = (A0.x + A1.x) + (A2.x + A3.x);
    S.y = (A0.y + A1.y) + (A2.y + A3.y);
    S.z = (A0.z + A1.z) + (A2.z + A3.z);
    S.w = (A0.w + A1.w) + (A2.w + A3.w);
    S.x += __shfl_xor(S.x, 32); S.y += __shfl_xor(S.y, 32);
    S.z += __shfl_xor(S.z, 32); S.w += __shfl_xor(S.w, 32);
    S.x += __shfl_xor(S.x, 16); S.y += __shfl_xor(S.y, 16);
    S.z += __shfl_xor(S.z, 16); S.w += __shfl_xor(S.w, 16);
    if (lane < 16) {
      float4 E = ((const float4*)(ego_in + (size_t)r * D))[q];
      float4 H;
      H.x = E.x * S.x; H.y = E.y * S.y; H.z = E.z * S.z; H.w = E.w * S.w;
      ((float4*)sS[w])[q] = S;
      ((float4*)sH[w])[q] = H;
    }
    // same-wave LDS write -> read (wave-ordered; no block sync needed)
    float acc = bias;
    #pragma unroll
    for (int jj = 0; jj < 64; ++jj)
      acc = fmaf(sWg[lane][jj], sS[w][jj], fmaf(sWb[lane][jj], sH[w][jj], acc));
    ego_out[(size_t)r * D + lane] = acc;
    bf_out[(size_t)r * D + lane] = f2bf(acc);
  }
}

// ---------- mid-path (unchanged) ----------
__global__ __launch_bounds__(256) void scatter_kernel(
    const int* __restrict__ row, const int* __restrict__ col,
    const float* __restrict__ val, int* __restrict__ cursor,
    int2* __restrict__ epair) {
  unsigned e = blockIdx.x * 256u + threadIdx.x;
  if (e >= NNZ) return;
  int r = row[e];
  int pos = atomicAdd(&cursor[r], 1);
  int2 p; p.x = col[e]; p.y = __float_as_int(val[e]);
  epair[pos] = p;
}

__global__ __launch_bounds__(1024) void spmm_xform_kernel(
    const int* __restrict__ row_ptr, const int2* __restrict__ epair,
    const float* __restrict__ ego_in, float* __restrict__ ego_out,
    const float* __restrict__ Wg, const float* __restrict__ bg,
    const float* __restrict__ Wb, const float* __restrict__ bb) {
  __shared__ float sWg[64][65];
  __shared__ float sWb[64][65];
  __shared__ float sS[16][64];
  __shared__ float sH[16][64];
  int t = threadIdx.x;
  for (int i = t; i < 4096; i += 1024) {
    sWg[i >> 6][i & 63] = Wg[i];
    sWb[i >> 6][i & 63] = Wb[i];
  }
  __syncthreads();
  int lane = t & 63;
  int w = t >> 6;
  int r = blockIdx.x * 16 + w;
  int rp0 = row_ptr[r], rp1 = row_ptr[r + 1];
  float a0 = 0.f, a1 = 0.f, a2 = 0.f, a3 = 0.f;
  for (int e0 = rp0; e0 < rp1; e0 += 64) {
    int n = rp1 - e0; if (n > 64) n = 64;
    int ce = 0; float ve = 0.f;
    if (lane < n) {
      int2 p = epair[e0 + lane];
      ce = p.x; ve = __int_as_float(p.y);
    }
    int j = 0;
    for (; j + 4 <= n; j += 4) {
      int   c0 = __shfl(ce, j),     c1 = __shfl(ce, j + 1);
      int   c2 = __shfl(ce, j + 2), c3 = __shfl(ce, j + 3);
      float v0 = __shfl(ve, j),     v1 = __shfl(ve, j + 1);
      float v2 = __shfl(ve, j + 2), v3 = __shfl(ve, j + 3);
      float g0 = ego_in[c0 * D + lane], g1 = ego_in[c1 * D + lane];
      float g2 = ego_in[c2 * D + lane], g3 = ego_in[c3 * D + lane];
      a0 = fmaf(v0, g0, a0); a1 = fmaf(v1, g1, a1);
      a2 = fmaf(v2, g2, a2); a3 = fmaf(v3, g3, a3);
    }
    for (; j < n; ++j) {
      int c = __shfl(ce, j); float v = __shfl(ve, j);
      a0 = fmaf(v, ego_in[c * D + lane], a0);
    }
  }
  float s = (a0 + a1) + (a2 + a3);
  float e = ego_in[r * D + lane];
  sS[w][lane] = s;
  sH[w][lane] = e * s;
  float acc = bg[lane] + bb[lane];
  #pragma unroll
  for (int j = 0; j < 64; ++j)
    acc = fmaf(sWg[lane][j], sS[w][j], fmaf(sWb[lane][j], sH[w][j], acc));
  ego_out[r * D + lane] = acc;
}

// ---------- atomic fallback ----------
__global__ __launch_bounds__(256) void spmm_atomic_kernel(
    const int* __restrict__ row, const int* __restrict__ col,
    const float* __restrict__ val, const float* __restrict__ ego,
    float* __restrict__ side) {
  unsigned tid = blockIdx.x * 256u + threadIdx.x;
  unsigned e = tid >> 6, d = tid & 63u;
  if (e >= NNZ) return;
  atomicAdd(&side[row[e] * D + d], val[e] * ego[col[e] * D + d]);
}

__global__ __launch_bounds__(256) void transform_kernel(
    const float* __restrict__ side, float* __restrict__ ego,
    const float* __restrict__ Wg, const float* __restrict__ bg,
    const float* __restrict__ Wb, const float* __restrict__ bb) {
  __shared__ float sWg[64][65];
  __shared__ float sWb[64][65];
  __shared__ float sS[4][64];
  __shared__ float sH[4][64];
  int t = threadIdx.x;
  for (int i = t; i < 4096; i += 256) {
    sWg[i >> 6][i & 63] = Wg[i];
    sWb[i >> 6][i & 63] = Wb[i];
  }
  int w = t >> 6, d = t & 63;
  int r = blockIdx.x * 4 + w;
  float e = 0.f, s = 0.f;
  if (r < NTOT) { e = ego[r * D + d]; s = side[r * D + d]; }
  sS[w][d] = s;
  sH[w][d] = e * s;
  __syncthreads();
  float acc = bg[d] + bb[d];
  #pragma unroll
  for (int j = 0; j < 64; ++j)
    acc = fmaf(sWg[d][j], sS[w][j], fmaf(sWb[d][j], sH[w][j], acc));
  if (r < NTOT) ego[r * D + d] = acc;
}

// ---------- output gathers ----------
__global__ void gather0_kernel(const int* __restrict__ users, const int* __restrict__ pos,
                               const int* __restrict__ neg, const float* __restrict__ ego,
                               float* __restrict__ out) {
  unsigned tid = blockIdx.x * 256u + threadIdx.x;
  unsigned d = tid & 63u, b = (tid >> 6) & 1023u, t = tid >> 16;
  int idx = (t == 0u) ? users[b] : (t == 1u ? N_USERS + pos[b] : N_USERS + neg[b]);
  out[t * (B * 256) + b * 256 + d] = ego[idx * D + d];
}

__global__ void gather_norm_kernel(const int* __restrict__ users, const int* __restrict__ pos,
                                   const int* __restrict__ neg, const float* __restrict__ ego,
                                   float* __restrict__ out, int seg) {
  unsigned tid = blockIdx.x * 256u + threadIdx.x;
  unsigned d = tid & 63u, b = (tid >> 6) & 1023u, t = tid >> 16;
  int idx = (t == 0u) ? users[b] : (t == 1u ? N_USERS + pos[b] : N_USERS + neg[b]);
  float v = ego[idx * D + d];
  float sq = v * v;
  #pragma unroll
  for (int off = 32; off; off >>= 1) sq += __shfl_xor(sq, off);
  float nrm = fmaxf(sqrtf(sq), 1e-12f);
  out[t * (B * 256) + b * 256 + seg * 64 + d] = v / nrm;
}

extern "C" void kernel_launch(void* const* d_in, const int* in_sizes, int n_in,
                              void* d_out, int out_size, void* d_ws, size_t ws_size,
                              hipStream_t stream) {
  const int*   users    = (const int*)d_in[0];
  const int*   pos      = (const int*)d_in[1];
  const int*   neg      = (const int*)d_in[2];
  const int*   adj_row  = (const int*)d_in[3];
  const int*   adj_col  = (const int*)d_in[4];
  const float* adj_val  = (const float*)d_in[5];
  const float* user_emb = (const float*)d_in[6];
  const float* item_emb = (const float*)d_in[7];
  const float* gcn_W    = (const float*)d_in[8];
  const float* gcn_b    = (const float*)d_in[9];
  const float* bi_W     = (const float*)d_in[10];
  const float* bi_b     = (const float*)d_in[11];
  float* out = (float*)d_out;

  const size_t EG = (size_t)NTOT * D;

  float* ego0 = (float*)d_ws;
  float* ego1 = ego0 + EG;
  int2*  epair   = (int2*)(ego1 + EG);
  int*   X       = (int*)(epair + NNZ);
  int2*  temp    = (int2*)X;
  unsigned short* bf0 = (unsigned short*)X;
  unsigned short* bf1 = bf0 + EG;
  int*   row_ptr = X + 2 * (size_t)NNZ;
  int*   blk     = row_ptr + (NTOT + 1);
  int*   bcur    = blk + 2 * SCAN_BLOCKS;
  int*   perm    = bcur + NBUCK;
  int*   dhist   = perm + NTOT;
  int*   dcur    = dhist + 256;
  int*   counts  = (int*)ego1;
  const size_t WS_FULL = ((size_t)(2 * EG + 2 * (size_t)NNZ + 2 * (size_t)NNZ
                          + (NTOT + 1) + 2 * SCAN_BLOCKS + NBUCK
                          + NTOT + 512)) * 4;

  int*   m_row_ptr = (int*)(epair + NNZ);
  int*   m_cursor  = m_row_ptr + (NTOT + 1);
  int*   m_blk     = m_cursor + (NTOT + 1);
  const size_t WS_MID = ((size_t)(2 * EG + 2 * (size_t)NNZ
                         + 2 * (NTOT + 1) + 2 * SCAN_BLOCKS)) * 4;

  hipMemcpyAsync(ego0, user_emb, (size_t)N_USERS * D * sizeof(float),
                 hipMemcpyDeviceToDevice, stream);
  hipMemcpyAsync(ego0 + (size_t)N_USERS * D, item_emb,
                 (size_t)(NTOT - N_USERS) * D * sizeof(float),
                 hipMemcpyDeviceToDevice, stream);

  gather0_kernel<<<768, 256, 0, stream>>>(users, pos, neg, ego0, out);

  if (ws_size >= WS_FULL) {
    hipMemsetAsync(counts, 0, (size_t)NTOT * sizeof(int), stream);
    hipMemsetAsync(dhist, 0, 256 * sizeof(int), stream);
    hist_kernel<<<(NNZ + 255) / 256, 256, 0, stream>>>(adj_row, counts);
    scanA_kernel<<<SCAN_BLOCKS, 1024, 0, stream>>>(counts, row_ptr, blk);
    scanB_kernel<<<1, 128, 0, stream>>>(blk, blk + SCAN_BLOCKS);
    scanC2_kernel<<<SCAN_BLOCKS, 1024, 0, stream>>>(row_ptr, blk + SCAN_BLOCKS);
    bcur_init_kernel<<<(NBUCK + 255) / 256, 256, 0, stream>>>(row_ptr, bcur);
    binA_kernel<<<BINA_BLOCKS, 256, 0, stream>>>(adj_row, adj_col, adj_val, bcur, temp);
    binB_kernel<<<NBUCK, 1024, 0, stream>>>(row_ptr, temp, epair);
    sort_rows_kernel<<<NTOT / 8, 512, 0, stream>>>(row_ptr, epair);
    deg_hist_kernel<<<(NTOT + 255) / 256, 256, 0, stream>>>(row_ptr, dhist);
    deg_scan_kernel<<<1, 256, 0, stream>>>(dhist, dcur);
    deg_scatter_kernel<<<(NTOT + 255) / 256, 256, 0, stream>>>(row_ptr, dcur, perm);
    tobf_kernel<<<(NTOT * D / 4 + 255) / 256, 256, 0, stream>>>((const float4*)ego0,
                                                                (ushort4*)bf0);
    float* cur = ego0;  unsigned short* bcurr = bf0;
    float* nxt = ego1;  unsigned short* bnxt  = bf1;
    for (int k = 0; k < 3; ++k) {
      spmm_xform_bf_kernel<<<SPMM_GRID, 512, 0, stream>>>(
          perm, row_ptr, epair, cur, bcurr, nxt, bnxt,
          gcn_W + k * 4096, gcn_b + k * 64, bi_W + k * 4096, bi_b + k * 64);
      gather_norm_kernel<<<768, 256, 0, stream>>>(users, pos, neg, nxt, out, k + 1);
      float* tf = cur; cur = nxt; nxt = tf;
      unsigned short* tb = bcurr; bcurr = bnxt; bnxt = tb;
    }
  } else if (ws_size >= WS_MID) {
    hipMemsetAsync(counts, 0, (size_t)NTOT * sizeof(int), stream);
    hist_kernel<<<(NNZ + 255) / 256, 256, 0, stream>>>(adj_row, counts);
    scanA_kernel<<<SCAN_BLOCKS, 1024, 0, stream>>>(counts, m_row_ptr, m_blk);
    scanB_kernel<<<1, 128, 0, stream>>>(m_blk, m_blk + SCAN_BLOCKS);
    scanC_kernel<<<SCAN_BLOCKS, 1024, 0, stream>>>(m_row_ptr, m_cursor, m_blk + SCAN_BLOCKS);
    scatter_kernel<<<(NNZ + 255) / 256, 256, 0, stream>>>(adj_row, adj_col, adj_val,
                                                          m_cursor, epair);
    float* cur = ego0;
    float* nxt = ego1;
    for (int k = 0; k < 3; ++k) {
      spmm_xform_kernel<<<NTOT / 16, 1024, 0, stream>>>(
          m_row_ptr, epair, cur, nxt,
          gcn_W + k * 4096, gcn_b + k * 64, bi_W + k * 4096, bi_b + k * 64);
      gather_norm_kernel<<<768, 256, 0, stream>>>(users, pos, neg, nxt, out, k + 1);
      float* tf = cur; cur = nxt; nxt = tf;
    }
  } else {
    float* side = ego1;
    for (int k = 0; k < 3; ++k) {
      hipMemsetAsync(side, 0, (size_t)NTOT * D * sizeof(float), stream);
      spmm_atomic_kernel<<<(NNZ * 64) / 256, 256, 0, stream>>>(adj_row, adj_col, adj_val,
                                                               ego0, side);
      transform_kernel<<<(NTOT + 3) / 4, 256, 0, stream>>>(
          side, ego0, gcn_W + k * 4096, gcn_b + k * 64, bi_W + k * 4096, bi_b + k * 64);
      gather_norm_kernel<<<768, 256, 0, stream>>>(users, pos, neg, ego0, out, k + 1);
    }
  }
}

// Round 7
// 643.894 us; speedup vs baseline: 2.0519x; 2.0519x over previous
//
#include <hip/hip_runtime.h>

#define N_USERS 50000
#define NTOT    100000
#define D       64
#define NNZ     3200000
#define B       1024
#define SCAN_BLOCKS ((NTOT + 1023) / 1024)   // 98
#define NBUCK ((NTOT + 255) / 256)           // 391
#define EPB 4096
#define BINA_BLOCKS ((NNZ + EPB - 1) / EPB)  // 782

__device__ __forceinline__ unsigned short f2bf(float f) {
  unsigned u = __float_as_uint(f);
  unsigned r = (u + 0x7FFFu + ((u >> 16) & 1u)) >> 16;
  return (unsigned short)r;
}
__device__ __forceinline__ float bf2f(unsigned short s) {
  return __uint_as_float(((unsigned)s) << 16);
}

// ---------- CSR build ----------
__global__ __launch_bounds__(256) void hist_kernel(const int* __restrict__ row,
                                                   int* __restrict__ counts) {
  unsigned e = blockIdx.x * 256u + threadIdx.x;
  if (e < NNZ) atomicAdd(&counts[row[e]], 1);
}

__global__ __launch_bounds__(1024) void scanA_kernel(const int* __restrict__ counts,
                                                     int* __restrict__ row_ptr,
                                                     int* __restrict__ blk_sums) {
  __shared__ int s[1024];
  int t = threadIdx.x;
  int gid = blockIdx.x * 1024 + t;
  int x = (gid < NTOT) ? counts[gid] : 0;
  s[t] = x;
  __syncthreads();
  #pragma unroll
  for (int off = 1; off < 1024; off <<= 1) {
    int v = (t >= off) ? s[t - off] : 0;
    __syncthreads();
    s[t] += v;
    __syncthreads();
  }
  if (gid < NTOT) row_ptr[gid] = s[t] - x;
  if (t == 1023) blk_sums[blockIdx.x] = s[t];
}

__global__ __launch_bounds__(128) void scanB_kernel(int* __restrict__ blk_sums,
                                                    int* __restrict__ blk_off) {
  __shared__ int s[128];
  int t = threadIdx.x;
  int x = (t < SCAN_BLOCKS) ? blk_sums[t] : 0;
  s[t] = x;
  __syncthreads();
  #pragma unroll
  for (int off = 1; off < 128; off <<= 1) {
    int v = (t >= off) ? s[t - off] : 0;
    __syncthreads();
    s[t] += v;
    __syncthreads();
  }
  if (t < SCAN_BLOCKS) blk_off[t] = s[t] - x;
}

__global__ __launch_bounds__(1024) void scanC2_kernel(int* __restrict__ row_ptr,
                                                      const int* __restrict__ blk_off) {
  int gid = blockIdx.x * 1024 + threadIdx.x;
  if (gid < NTOT) row_ptr[gid] += blk_off[blockIdx.x];
  if (gid == 0) row_ptr[NTOT] = NNZ;
}

__global__ __launch_bounds__(1024) void scanC_kernel(int* __restrict__ row_ptr,
                                                     int* __restrict__ cursor,
                                                     const int* __restrict__ blk_off) {
  int gid = blockIdx.x * 1024 + threadIdx.x;
  if (gid < NTOT) {
    int v = row_ptr[gid] + blk_off[blockIdx.x];
    row_ptr[gid] = v;
    cursor[gid] = v;
  }
  if (gid == 0) row_ptr[NTOT] = NNZ;
}

__global__ __launch_bounds__(256) void bcur_init_kernel(const int* __restrict__ row_ptr,
                                                        int* __restrict__ bcur) {
  int t = blockIdx.x * 256 + threadIdx.x;
  if (t < NBUCK) bcur[t] = row_ptr[t << 8];
}

__global__ __launch_bounds__(256) void binA_kernel(
    const int* __restrict__ row, const int* __restrict__ col,
    const float* __restrict__ val, int* __restrict__ bcur,
    int2* __restrict__ temp) {
  __shared__ int hist[NBUCK];
  __shared__ int base[NBUCK];
  int t = threadIdx.x;
  for (int i = t; i < NBUCK; i += 256) hist[i] = 0;
  __syncthreads();
  int e0 = blockIdx.x * EPB + t;
  int xp[16], yb[16], bk[16], ofs[16];
  #pragma unroll
  for (int i = 0; i < 16; ++i) {
    int e = e0 + i * 256;
    bk[i] = -1;
    if (e < NNZ) {
      int r = row[e];
      int b = r >> 8;
      xp[i] = col[e] | ((r & 255) << 17);
      yb[i] = __float_as_int(val[e]);
      bk[i] = b;
      ofs[i] = atomicAdd(&hist[b], 1);
    }
  }
  __syncthreads();
  for (int i = t; i < NBUCK; i += 256) {
    int h = hist[i];
    base[i] = h ? atomicAdd(&bcur[i], h) : 0;
  }
  __syncthreads();
  #pragma unroll
  for (int i = 0; i < 16; ++i) {
    if (bk[i] >= 0) {
      int2 p; p.x = xp[i]; p.y = yb[i];
      temp[base[bk[i]] + ofs[i]] = p;
    }
  }
}

__global__ __launch_bounds__(1024) void binB_kernel(
    const int* __restrict__ row_ptr, const int2* __restrict__ temp,
    int2* __restrict__ epair) {
  __shared__ int cur[256];
  int b = blockIdx.x, t = threadIdx.x;
  int r0 = b << 8;
  int nr = min(256, NTOT - r0);
  if (t < nr) cur[t] = row_ptr[r0 + t];
  __syncthreads();
  int lo = row_ptr[r0], hi = row_ptr[r0 + nr];
  for (int i = lo + t; i < hi; i += 1024) {
    int2 p = temp[i];
    int rlow = (p.x >> 17) & 255;
    int pos = atomicAdd(&cur[rlow], 1);
    int2 q; q.x = p.x & 0x1FFFF; q.y = p.y;
    epair[pos] = q;
  }
}

// f32 ego -> bf16 shadow
__global__ __launch_bounds__(256) void tobf_kernel(const float4* __restrict__ src,
                                                   ushort4* __restrict__ dst) {
  int i = blockIdx.x * 256 + threadIdx.x;
  if (i < NTOT * D / 4) {
    float4 f = src[i];
    ushort4 o;
    o.x = f2bf(f.x); o.y = f2bf(f.y); o.z = f2bf(f.z); o.w = f2bf(f.w);
    dst[i] = o;
  }
}

// ---------- fused CSR SpMM (bf16, 16 lanes/edge, 8-deep gather pipeline) ----------
__global__ __launch_bounds__(512) void spmm_xform_bf_kernel(
    const int* __restrict__ row_ptr, const int2* __restrict__ epair,
    const float* __restrict__ ego_in, const unsigned short* __restrict__ bf_in,
    float* __restrict__ ego_out, unsigned short* __restrict__ bf_out,
    const float* __restrict__ Wg, const float* __restrict__ bg,
    const float* __restrict__ Wb, const float* __restrict__ bb) {
  __shared__ float sWg[64][65];
  __shared__ float sWb[64][65];
  __shared__ float sS[8][64];
  __shared__ float sH[8][64];
  int t = threadIdx.x;
  for (int i = t; i < 4096; i += 512) {
    sWg[i >> 6][i & 63] = Wg[i];
    sWb[i >> 6][i & 63] = Wb[i];
  }
  __syncthreads();

  int lane = t & 63;
  int w = t >> 6;                 // wave 0..7
  int r = blockIdx.x * 8 + w;
  int rp0 = row_ptr[r], rp1 = row_ptr[r + 1];
  int es = lane >> 4;             // edge sub-slot 0..3
  int q  = lane & 15;             // dim quad
  const ushort4* bfv = (const ushort4*)bf_in;

  float4 A0 = {0.f, 0.f, 0.f, 0.f}, A1 = A0, A2 = A0, A3 = A0;
  if (rp0 < rp1) {
    int last = rp1 - 1;
    // 32 edges per iteration, 8 independent (epair -> table) chains per lane.
    for (int j = rp0; j < rp1; j += 32) {
      int2 p0 = epair[min(j + es,      last)];
      int2 p1 = epair[min(j + 4 + es,  last)];
      int2 p2 = epair[min(j + 8 + es,  last)];
      int2 p3 = epair[min(j + 12 + es, last)];
      int2 p4 = epair[min(j + 16 + es, last)];
      int2 p5 = epair[min(j + 20 + es, last)];
      int2 p6 = epair[min(j + 24 + es, last)];
      int2 p7 = epair[min(j + 28 + es, last)];
      ushort4 u0 = bfv[p0.x * 16 + q];
      ushort4 u1 = bfv[p1.x * 16 + q];
      ushort4 u2 = bfv[p2.x * 16 + q];
      ushort4 u3 = bfv[p3.x * 16 + q];
      ushort4 u4 = bfv[p4.x * 16 + q];
      ushort4 u5 = bfv[p5.x * 16 + q];
      ushort4 u6 = bfv[p6.x * 16 + q];
      ushort4 u7 = bfv[p7.x * 16 + q];
      float v0 = (j + es      < rp1) ? __int_as_float(p0.y) : 0.f;
      float v1 = (j + 4 + es  < rp1) ? __int_as_float(p1.y) : 0.f;
      float v2 = (j + 8 + es  < rp1) ? __int_as_float(p2.y) : 0.f;
      float v3 = (j + 12 + es < rp1) ? __int_as_float(p3.y) : 0.f;
      float v4 = (j + 16 + es < rp1) ? __int_as_float(p4.y) : 0.f;
      float v5 = (j + 20 + es < rp1) ? __int_as_float(p5.y) : 0.f;
      float v6 = (j + 24 + es < rp1) ? __int_as_float(p6.y) : 0.f;
      float v7 = (j + 28 + es < rp1) ? __int_as_float(p7.y) : 0.f;
      A0.x = fmaf(v0, bf2f(u0.x), A0.x); A0.y = fmaf(v0, bf2f(u0.y), A0.y);
      A0.z = fmaf(v0, bf2f(u0.z), A0.z); A0.w = fmaf(v0, bf2f(u0.w), A0.w);
      A1.x = fmaf(v1, bf2f(u1.x), A1.x); A1.y = fmaf(v1, bf2f(u1.y), A1.y);
      A1.z = fmaf(v1, bf2f(u1.z), A1.z); A1.w = fmaf(v1, bf2f(u1.w), A1.w);
      A2.x = fmaf(v2, bf2f(u2.x), A2.x); A2.y = fmaf(v2, bf2f(u2.y), A2.y);
      A2.z = fmaf(v2, bf2f(u2.z), A2.z); A2.w = fmaf(v2, bf2f(u2.w), A2.w);
      A3.x = fmaf(v3, bf2f(u3.x), A3.x); A3.y = fmaf(v3, bf2f(u3.y), A3.y);
      A3.z = fmaf(v3, bf2f(u3.z), A3.z); A3.w = fmaf(v3, bf2f(u3.w), A3.w);
      A0.x = fmaf(v4, bf2f(u4.x), A0.x); A0.y = fmaf(v4, bf2f(u4.y), A0.y);
      A0.z = fmaf(v4, bf2f(u4.z), A0.z); A0.w = fmaf(v4, bf2f(u4.w), A0.w);
      A1.x = fmaf(v5, bf2f(u5.x), A1.x); A1.y = fmaf(v5, bf2f(u5.y), A1.y);
      A1.z = fmaf(v5, bf2f(u5.z), A1.z); A1.w = fmaf(v5, bf2f(u5.w), A1.w);
      A2.x = fmaf(v6, bf2f(u6.x), A2.x); A2.y = fmaf(v6, bf2f(u6.y), A2.y);
      A2.z = fmaf(v6, bf2f(u6.z), A2.z); A2.w = fmaf(v6, bf2f(u6.w), A2.w);
      A3.x = fmaf(v7, bf2f(u7.x), A3.x); A3.y = fmaf(v7, bf2f(u7.y), A3.y);
      A3.z = fmaf(v7, bf2f(u7.z), A3.z); A3.w = fmaf(v7, bf2f(u7.w), A3.w);
    }
  }
  float4 S;
  S.x = (A0.x + A1.x) + (A2.x + A3.x);
  S.y = (A0.y + A1.y) + (A2.y + A3.y);
  S.z = (A0.z + A1.z) + (A2.z + A3.z);
  S.w = (A0.w + A1.w) + (A2.w + A3.w);
  S.x += __shfl_xor(S.x, 32); S.y += __shfl_xor(S.y, 32);
  S.z += __shfl_xor(S.z, 32); S.w += __shfl_xor(S.w, 32);
  S.x += __shfl_xor(S.x, 16); S.y += __shfl_xor(S.y, 16);
  S.z += __shfl_xor(S.z, 16); S.w += __shfl_xor(S.w, 16);
  if (lane < 16) {
    float4 E = ((const float4*)(ego_in + (size_t)r * D))[q];
    float4 H;
    H.x = E.x * S.x; H.y = E.y * S.y; H.z = E.z * S.z; H.w = E.w * S.w;
    ((float4*)sS[w])[q] = S;
    ((float4*)sH[w])[q] = H;
  }
  // same-wave LDS write -> read (wave-ordered)
  float acc = bg[lane] + bb[lane];
  #pragma unroll
  for (int jj = 0; jj < 64; ++jj)
    acc = fmaf(sWg[lane][jj], sS[w][jj], fmaf(sWb[lane][jj], sH[w][jj], acc));
  ego_out[(size_t)r * D + lane] = acc;
  bf_out[(size_t)r * D + lane] = f2bf(acc);
}

// ---------- mid-path ----------
__global__ __launch_bounds__(256) void scatter_kernel(
    const int* __restrict__ row, const int* __restrict__ col,
    const float* __restrict__ val, int* __restrict__ cursor,
    int2* __restrict__ epair) {
  unsigned e = blockIdx.x * 256u + threadIdx.x;
  if (e >= NNZ) return;
  int r = row[e];
  int pos = atomicAdd(&cursor[r], 1);
  int2 p; p.x = col[e]; p.y = __float_as_int(val[e]);
  epair[pos] = p;
}

__global__ __launch_bounds__(1024) void spmm_xform_kernel(
    const int* __restrict__ row_ptr, const int2* __restrict__ epair,
    const float* __restrict__ ego_in, float* __restrict__ ego_out,
    const float* __restrict__ Wg, const float* __restrict__ bg,
    const float* __restrict__ Wb, const float* __restrict__ bb) {
  __shared__ float sWg[64][65];
  __shared__ float sWb[64][65];
  __shared__ float sS[16][64];
  __shared__ float sH[16][64];
  int t = threadIdx.x;
  for (int i = t; i < 4096; i += 1024) {
    sWg[i >> 6][i & 63] = Wg[i];
    sWb[i >> 6][i & 63] = Wb[i];
  }
  __syncthreads();
  int lane = t & 63;
  int w = t >> 6;
  int r = blockIdx.x * 16 + w;
  int rp0 = row_ptr[r], rp1 = row_ptr[r + 1];
  float a0 = 0.f, a1 = 0.f, a2 = 0.f, a3 = 0.f;
  for (int e0 = rp0; e0 < rp1; e0 += 64) {
    int n = rp1 - e0; if (n > 64) n = 64;
    int ce = 0; float ve = 0.f;
    if (lane < n) {
      int2 p = epair[e0 + lane];
      ce = p.x; ve = __int_as_float(p.y);
    }
    int j = 0;
    for (; j + 4 <= n; j += 4) {
      int   c0 = __shfl(ce, j),     c1 = __shfl(ce, j + 1);
      int   c2 = __shfl(ce, j + 2), c3 = __shfl(ce, j + 3);
      float v0 = __shfl(ve, j),     v1 = __shfl(ve, j + 1);
      float v2 = __shfl(ve, j + 2), v3 = __shfl(ve, j + 3);
      float g0 = ego_in[c0 * D + lane], g1 = ego_in[c1 * D + lane];
      float g2 = ego_in[c2 * D + lane], g3 = ego_in[c3 * D + lane];
      a0 = fmaf(v0, g0, a0); a1 = fmaf(v1, g1, a1);
      a2 = fmaf(v2, g2, a2); a3 = fmaf(v3, g3, a3);
    }
    for (; j < n; ++j) {
      int c = __shfl(ce, j); float v = __shfl(ve, j);
      a0 = fmaf(v, ego_in[c * D + lane], a0);
    }
  }
  float s = (a0 + a1) + (a2 + a3);
  float e = ego_in[r * D + lane];
  sS[w][lane] = s;
  sH[w][lane] = e * s;
  float acc = bg[lane] + bb[lane];
  #pragma unroll
  for (int j = 0; j < 64; ++j)
    acc = fmaf(sWg[lane][j], sS[w][j], fmaf(sWb[lane][j], sH[w][j], acc));
  ego_out[r * D + lane] = acc;
}

// ---------- atomic fallback ----------
__global__ __launch_bounds__(256) void spmm_atomic_kernel(
    const int* __restrict__ row, const int* __restrict__ col,
    const float* __restrict__ val, const float* __restrict__ ego,
    float* __restrict__ side) {
  unsigned tid = blockIdx.x * 256u + threadIdx.x;
  unsigned e = tid >> 6, d = tid & 63u;
  if (e >= NNZ) return;
  atomicAdd(&side[row[e] * D + d], val[e] * ego[col[e] * D + d]);
}

__global__ __launch_bounds__(256) void transform_kernel(
    const float* __restrict__ side, float* __restrict__ ego,
    const float* __restrict__ Wg, const float* __restrict__ bg,
    const float* __restrict__ Wb, const float* __restrict__ bb) {
  __shared__ float sWg[64][65];
  __shared__ float sWb[64][65];
  __shared__ float sS[4][64];
  __shared__ float sH[4][64];
  int t = threadIdx.x;
  for (int i = t; i < 4096; i += 256) {
    sWg[i >> 6][i & 63] = Wg[i];
    sWb[i >> 6][i & 63] = Wb[i];
  }
  int w = t >> 6, d = t & 63;
  int r = blockIdx.x * 4 + w;
  float e = 0.f, s = 0.f;
  if (r < NTOT) { e = ego[r * D + d]; s = side[r * D + d]; }
  sS[w][d] = s;
  sH[w][d] = e * s;
  __syncthreads();
  float acc = bg[d] + bb[d];
  #pragma unroll
  for (int j = 0; j < 64; ++j)
    acc = fmaf(sWg[d][j], sS[w][j], fmaf(sWb[d][j], sH[w][j], acc));
  if (r < NTOT) ego[r * D + d] = acc;
}

// ---------- output gathers ----------
__global__ void gather0_kernel(const int* __restrict__ users, const int* __restrict__ pos,
                               const int* __restrict__ neg, const float* __restrict__ ego,
                               float* __restrict__ out) {
  unsigned tid = blockIdx.x * 256u + threadIdx.x;
  unsigned d = tid & 63u, b = (tid >> 6) & 1023u, t = tid >> 16;
  int idx = (t == 0u) ? users[b] : (t == 1u ? N_USERS + pos[b] : N_USERS + neg[b]);
  out[t * (B * 256) + b * 256 + d] = ego[idx * D + d];
}

__global__ void gather_norm_kernel(const int* __restrict__ users, const int* __restrict__ pos,
                                   const int* __restrict__ neg, const float* __restrict__ ego,
                                   float* __restrict__ out, int seg) {
  unsigned tid = blockIdx.x * 256u + threadIdx.x;
  unsigned d = tid & 63u, b = (tid >> 6) & 1023u, t = tid >> 16;
  int idx = (t == 0u) ? users[b] : (t == 1u ? N_USERS + pos[b] : N_USERS + neg[b]);
  float v = ego[idx * D + d];
  float sq = v * v;
  #pragma unroll
  for (int off = 32; off; off >>= 1) sq += __shfl_xor(sq, off);
  float nrm = fmaxf(sqrtf(sq), 1e-12f);
  out[t * (B * 256) + b * 256 + seg * 64 + d] = v / nrm;
}

extern "C" void kernel_launch(void* const* d_in, const int* in_sizes, int n_in,
                              void* d_out, int out_size, void* d_ws, size_t ws_size,
                              hipStream_t stream) {
  const int*   users    = (const int*)d_in[0];
  const int*   pos      = (const int*)d_in[1];
  const int*   neg      = (const int*)d_in[2];
  const int*   adj_row  = (const int*)d_in[3];
  const int*   adj_col  = (const int*)d_in[4];
  const float* adj_val  = (const float*)d_in[5];
  const float* user_emb = (const float*)d_in[6];
  const float* item_emb = (const float*)d_in[7];
  const float* gcn_W    = (const float*)d_in[8];
  const float* gcn_b    = (const float*)d_in[9];
  const float* bi_W     = (const float*)d_in[10];
  const float* bi_b     = (const float*)d_in[11];
  float* out = (float*)d_out;

  const size_t EG = (size_t)NTOT * D;

  float* ego0 = (float*)d_ws;
  float* ego1 = ego0 + EG;
  int2*  epair   = (int2*)(ego1 + EG);
  int*   X       = (int*)(epair + NNZ);
  int2*  temp    = (int2*)X;
  unsigned short* bf0 = (unsigned short*)X;
  unsigned short* bf1 = bf0 + EG;
  int*   row_ptr = X + 2 * (size_t)NNZ;
  int*   blk     = row_ptr + (NTOT + 1);
  int*   bcur    = blk + 2 * SCAN_BLOCKS;
  int*   counts  = (int*)ego1;
  const size_t WS_FULL = ((size_t)(2 * EG + 2 * (size_t)NNZ + 2 * (size_t)NNZ
                          + (NTOT + 1) + 2 * SCAN_BLOCKS + NBUCK)) * 4;

  int*   m_row_ptr = (int*)(epair + NNZ);
  int*   m_cursor  = m_row_ptr + (NTOT + 1);
  int*   m_blk     = m_cursor + (NTOT + 1);
  const size_t WS_MID = ((size_t)(2 * EG + 2 * (size_t)NNZ
                         + 2 * (NTOT + 1) + 2 * SCAN_BLOCKS)) * 4;

  hipMemcpyAsync(ego0, user_emb, (size_t)N_USERS * D * sizeof(float),
                 hipMemcpyDeviceToDevice, stream);
  hipMemcpyAsync(ego0 + (size_t)N_USERS * D, item_emb,
                 (size_t)(NTOT - N_USERS) * D * sizeof(float),
                 hipMemcpyDeviceToDevice, stream);

  gather0_kernel<<<768, 256, 0, stream>>>(users, pos, neg, ego0, out);

  if (ws_size >= WS_FULL) {
    hipMemsetAsync(counts, 0, (size_t)NTOT * sizeof(int), stream);
    hist_kernel<<<(NNZ + 255) / 256, 256, 0, stream>>>(adj_row, counts);
    scanA_kernel<<<SCAN_BLOCKS, 1024, 0, stream>>>(counts, row_ptr, blk);
    scanB_kernel<<<1, 128, 0, stream>>>(blk, blk + SCAN_BLOCKS);
    scanC2_kernel<<<SCAN_BLOCKS, 1024, 0, stream>>>(row_ptr, blk + SCAN_BLOCKS);
    bcur_init_kernel<<<(NBUCK + 255) / 256, 256, 0, stream>>>(row_ptr, bcur);
    binA_kernel<<<BINA_BLOCKS, 256, 0, stream>>>(adj_row, adj_col, adj_val, bcur, temp);
    binB_kernel<<<NBUCK, 1024, 0, stream>>>(row_ptr, temp, epair);
    tobf_kernel<<<(NTOT * D / 4 + 255) / 256, 256, 0, stream>>>((const float4*)ego0,
                                                                (ushort4*)bf0);
    float* cur = ego0;  unsigned short* bcurr = bf0;
    float* nxt = ego1;  unsigned short* bnxt  = bf1;
    for (int k = 0; k < 3; ++k) {
      spmm_xform_bf_kernel<<<NTOT / 8, 512, 0, stream>>>(
          row_ptr, epair, cur, bcurr, nxt, bnxt,
          gcn_W + k * 4096, gcn_b + k * 64, bi_W + k * 4096, bi_b + k * 64);
      gather_norm_kernel<<<768, 256, 0, stream>>>(users, pos, neg, nxt, out, k + 1);
      float* tf = cur; cur = nxt; nxt = tf;
      unsigned short* tb = bcurr; bcurr = bnxt; bnxt = tb;
    }
  } else if (ws_size >= WS_MID) {
    hipMemsetAsync(counts, 0, (size_t)NTOT * sizeof(int), stream);
    hist_kernel<<<(NNZ + 255) / 256, 256, 0, stream>>>(adj_row, counts);
    scanA_kernel<<<SCAN_BLOCKS, 1024, 0, stream>>>(counts, m_row_ptr, m_blk);
    scanB_kernel<<<1, 128, 0, stream>>>(m_blk, m_blk + SCAN_BLOCKS);
    scanC_kernel<<<SCAN_BLOCKS, 1024, 0, stream>>>(m_row_ptr, m_cursor, m_blk + SCAN_BLOCKS);
    scatter_kernel<<<(NNZ + 255) / 256, 256, 0, stream>>>(adj_row, adj_col, adj_val,
                                                          m_cursor, epair);
    float* cur = ego0;
    float* nxt = ego1;
    for (int k = 0; k < 3; ++k) {
      spmm_xform_kernel<<<NTOT / 16, 1024, 0, stream>>>(
          m_row_ptr, epair, cur, nxt,
          gcn_W + k * 4096, gcn_b + k * 64, bi_W + k * 4096, bi_b + k * 64);
      gather_norm_kernel<<<768, 256, 0, stream>>>(users, pos, neg, nxt, out, k + 1);
      float* tf = cur; cur = nxt; nxt = tf;
    }
  } else {
    float* side = ego1;
    for (int k = 0; k < 3; ++k) {
      hipMemsetAsync(side, 0, (size_t)NTOT * D * sizeof(float), stream);
      spmm_atomic_kernel<<<(NNZ * 64) / 256, 256, 0, stream>>>(adj_row, adj_col, adj_val,
                                                               ego0, side);
      transform_kernel<<<(NTOT + 3) / 4, 256, 0, stream>>>(
          side, ego0, gcn_W + k * 4096, gcn_b + k * 64, bi_W + k * 4096, bi_b + k * 64);
      gather_norm_kernel<<<768, 256, 0, stream>>>(users, pos, neg, ego0, out, k + 1);
    }
  }
}